// Round 2
// baseline (140420.544 us; speedup 1.0000x reference)
//
#include <hip/hip_runtime.h>
#include <math.h>

// Problem constants
static constexpr int S_LEN = 512;
static constexpr int BATCH = 256;
static constexpr int IDIM  = 256;
static constexpr int HDIM  = 1024;
static constexpr int SWID  = 256;
static constexpr int SDEP  = 100;
static constexpr int K1    = IDIM + SWID;   // 512
static constexpr int KTOT  = K1 + HDIM;     // 1536

static constexpr int NBLK = 256;
static constexpr int NTHR = 256;

// Phase A (gates GEMM) tile: 32 batches x 32 j x 4 gates, K-chunks of 16
static constexpr int A_BM = 32;
static constexpr int A_BJ = 32;
static constexpr int A_KB = 16;

// Phase BC tile: 8 batches x 32 stack cols per block (32 x 8 = 256 blocks)
static constexpr int BC_BB = 8;
static constexpr int BC_BJ = 32;
static constexpr int BC_KB = 64;

struct SharedA {
    float As[A_KB][A_BM + 4];        // [kk][b]
    float Bs[A_KB][A_BJ * 4 + 4];    // [kk][j*4+g]
};
struct SharedBC {
    float Hs[BC_BB][HDIM + 4];       // 8 x 1028
    float Dsh[BC_KB][BC_BJ + 1];     // [kk][j]
    float logits[BC_BB][3];
    float ctrl[BC_BB][3];            // push, pop, noop
};
union SharedU {
    SharedA a;
    SharedBC bc;
};

__device__ __forceinline__ float sigmoidf_(float v) {
    return 1.0f / (1.0f + expf(-v));
}

// Software grid barrier: monotonic counter, device(agent)-scope atomics.
// All 256 blocks are co-resident (1 block/CU on 256 CUs), so spinning is safe.
__device__ __forceinline__ void grid_barrier(unsigned* cnt, unsigned target) {
    __syncthreads();
    if (threadIdx.x == 0) {
        __threadfence();  // release all prior global writes (device scope)
        __hip_atomic_fetch_add(cnt, 1u, __ATOMIC_ACQ_REL, __HIP_MEMORY_SCOPE_AGENT);
        while (__hip_atomic_load(cnt, __ATOMIC_ACQUIRE, __HIP_MEMORY_SCOPE_AGENT) < target)
            __builtin_amdgcn_s_sleep(2);
        __threadfence();
    }
    __syncthreads();
}

__global__ void init_barrier_kernel(unsigned* cnt) {
    if (threadIdx.x == 0) *cnt = 0u;
}

__global__ __launch_bounds__(NTHR) void stackrnn_kernel(
    const float* __restrict__ x,
    const float* __restrict__ h0,
    const float* __restrict__ c0,
    const float* __restrict__ stack0,
    const float* __restrict__ W_ih,
    const float* __restrict__ W_hh,
    const float* __restrict__ b_ih,
    const float* __restrict__ b_hh,
    const float* __restrict__ A_w,
    const float* __restrict__ A_b,
    const float* __restrict__ D_w,
    const float* __restrict__ D_b,
    float* __restrict__ out,
    float* __restrict__ ws_stack,
    float* __restrict__ ws_c,
    unsigned* __restrict__ bar)
{
    __shared__ SharedU sm;
    const int tid = threadIdx.x;
    const int bid = blockIdx.x;
    const int gtid = bid * NTHR + tid;
    const int gstride = NBLK * NTHR;  // 65536
    unsigned bar_target = NBLK;

    // ---- init workspace state from stack0 / c0 (ws is poisoned every call) ----
    {
        const float4* src = (const float4*)stack0;
        float4* dst = (float4*)ws_stack;
        const int n4 = (BATCH * SDEP * SWID) / 4;
        for (int i = gtid; i < n4; i += gstride) dst[i] = src[i];
        const float4* src2 = (const float4*)c0;
        float4* dst2 = (float4*)ws_c;
        const int c4 = (BATCH * HDIM) / 4;
        for (int i = gtid; i < c4; i += gstride) dst2[i] = src2[i];
    }
    grid_barrier(bar, bar_target); bar_target += NBLK;

    for (int t = 0; t < S_LEN; ++t) {
        // ================= Phase A: gates GEMM + LSTM cell =================
        {
            const int bt = bid >> 5;      // 0..7  : batch tile
            const int jt = bid & 31;      // 0..31 : j tile
            const int tx = tid & 31;      // j_local
            const int ty = tid >> 5;      // 0..7  : group of 4 batch rows
            const float* hprev = (t == 0) ? h0 : (out + (size_t)(t - 1) * BATCH * HDIM);

            float acc[4][4];
            #pragma unroll
            for (int r = 0; r < 4; ++r)
                #pragma unroll
                for (int g = 0; g < 4; ++g) acc[r][g] = 0.0f;

            const int a_bl = tid >> 3;           // 0..31
            const int a_kk = (tid & 7) * 2;      // 0,2,...,14
            const int b_cl = tid >> 1;           // 0..127 (= j_local*4 + gate)
            const int b_kb = (tid & 1) * 8;      // 0 or 8
            const int b_g  = b_cl & 3;
            const int b_jl = b_cl >> 2;
            const int b_col = b_g * HDIM + jt * A_BJ + b_jl;

            for (int kc = 0; kc < KTOT / A_KB; ++kc) {
                const int k0 = kc * A_KB;
                // stage A chunk: xin/h rows, transposed to [kk][b]
                {
                    const int b = bt * A_BM + a_bl;
                    const int k = k0 + a_kk;
                    float2 v;
                    if (k < IDIM) {
                        v = *(const float2*)(x + (size_t)t * BATCH * IDIM + (size_t)b * IDIM + k);
                    } else if (k < K1) {
                        v = *(const float2*)(ws_stack + (size_t)b * SDEP * SWID + (k - IDIM));
                    } else {
                        v = *(const float2*)(hprev + (size_t)b * HDIM + (k - K1));
                    }
                    sm.a.As[a_kk][a_bl]     = v.x;
                    sm.a.As[a_kk + 1][a_bl] = v.y;
                }
                // stage B chunk: weights, transposed to [kk][col_local]
                {
                    const float* wsrc;
                    if (k0 < K1) wsrc = W_ih + (size_t)b_col * K1 + (k0 + b_kb);
                    else         wsrc = W_hh + (size_t)b_col * HDIM + (k0 - K1 + b_kb);
                    float4 v0 = *(const float4*)(wsrc);
                    float4 v1 = *(const float4*)(wsrc + 4);
                    sm.a.Bs[b_kb + 0][b_cl] = v0.x;
                    sm.a.Bs[b_kb + 1][b_cl] = v0.y;
                    sm.a.Bs[b_kb + 2][b_cl] = v0.z;
                    sm.a.Bs[b_kb + 3][b_cl] = v0.w;
                    sm.a.Bs[b_kb + 4][b_cl] = v1.x;
                    sm.a.Bs[b_kb + 5][b_cl] = v1.y;
                    sm.a.Bs[b_kb + 6][b_cl] = v1.z;
                    sm.a.Bs[b_kb + 7][b_cl] = v1.w;
                }
                __syncthreads();
                #pragma unroll
                for (int kk = 0; kk < A_KB; ++kk) {
                    float4 av = *(const float4*)&sm.a.As[kk][ty * 4];
                    float4 bv = *(const float4*)&sm.a.Bs[kk][tx * 4];
                    acc[0][0] += av.x * bv.x; acc[0][1] += av.x * bv.y;
                    acc[0][2] += av.x * bv.z; acc[0][3] += av.x * bv.w;
                    acc[1][0] += av.y * bv.x; acc[1][1] += av.y * bv.y;
                    acc[1][2] += av.y * bv.z; acc[1][3] += av.y * bv.w;
                    acc[2][0] += av.z * bv.x; acc[2][1] += av.z * bv.y;
                    acc[2][2] += av.z * bv.z; acc[2][3] += av.z * bv.w;
                    acc[3][0] += av.w * bv.x; acc[3][1] += av.w * bv.y;
                    acc[3][2] += av.w * bv.z; acc[3][3] += av.w * bv.w;
                }
                __syncthreads();
            }
            // LSTM epilogue
            const int j = jt * A_BJ + tx;
            const float bias_i = b_ih[0 * HDIM + j] + b_hh[0 * HDIM + j];
            const float bias_f = b_ih[1 * HDIM + j] + b_hh[1 * HDIM + j];
            const float bias_g = b_ih[2 * HDIM + j] + b_hh[2 * HDIM + j];
            const float bias_o = b_ih[3 * HDIM + j] + b_hh[3 * HDIM + j];
            float* outrow = out + (size_t)t * BATCH * HDIM;
            #pragma unroll
            for (int r = 0; r < 4; ++r) {
                const int b = bt * A_BM + ty * 4 + r;
                const float gi = sigmoidf_(acc[r][0] + bias_i);
                const float gf = sigmoidf_(acc[r][1] + bias_f);
                const float gg = tanhf(acc[r][2] + bias_g);
                const float go = sigmoidf_(acc[r][3] + bias_o);
                const size_t idx = (size_t)b * HDIM + j;
                const float cp = ws_c[idx];
                const float cn = gf * cp + gi * gg;
                const float hn = go * tanhf(cn);
                ws_c[idx] = cn;
                outrow[idx] = hn;
            }
        }
        grid_barrier(bar, bar_target); bar_target += NBLK;

        // ================= Phase BC: controls, d, stack update =================
        {
            const int bg = bid >> 3;    // 0..31 : batch group (8 batches)
            const int jg = bid & 7;     // 0..7  : col group (32 cols)
            const int tx = tid & 31;    // j_local
            const int ty = tid >> 5;    // 0..7  : b_local
            const float* hcur = out + (size_t)t * BATCH * HDIM + (size_t)bg * BC_BB * HDIM;

            // stage h rows (8 x 1024)
            #pragma unroll
            for (int i = 0; i < BC_BB; ++i) {
                float4 v = *(const float4*)(hcur + (size_t)i * HDIM + tid * 4);
                *(float4*)&sm.bc.Hs[i][tid * 4] = v;
            }
            __syncthreads();

            // control logits: partial dot over k-chunk tx*32..+31, reduce over tx
            {
                float p0 = 0.f, p1 = 0.f, p2 = 0.f;
                const int kbase = tx * 32;
                #pragma unroll
                for (int kk = 0; kk < 32; ++kk) {
                    const float h = sm.bc.Hs[ty][kbase + kk];
                    p0 += h * A_w[0 * HDIM + kbase + kk];
                    p1 += h * A_w[1 * HDIM + kbase + kk];
                    p2 += h * A_w[2 * HDIM + kbase + kk];
                }
                #pragma unroll
                for (int off = 16; off > 0; off >>= 1) {
                    p0 += __shfl_xor(p0, off, 64);
                    p1 += __shfl_xor(p1, off, 64);
                    p2 += __shfl_xor(p2, off, 64);
                }
                if (tx == 0) {
                    sm.bc.logits[ty][0] = p0;
                    sm.bc.logits[ty][1] = p1;
                    sm.bc.logits[ty][2] = p2;
                }
            }

            // D projection tile: d[b=ty][j=jg*32+tx], K=1024 in chunks of 64
            float dacc = 0.0f;
            const int d_row = tid >> 3;          // 0..31
            const int d_kb  = (tid & 7) * 8;     // 0..56
            for (int kc = 0; kc < HDIM / BC_KB; ++kc) {
                const float* dsrc = D_w + (size_t)(jg * BC_BJ + d_row) * HDIM + kc * BC_KB + d_kb;
                float4 v0 = *(const float4*)dsrc;
                float4 v1 = *(const float4*)(dsrc + 4);
                sm.bc.Dsh[d_kb + 0][d_row] = v0.x;
                sm.bc.Dsh[d_kb + 1][d_row] = v0.y;
                sm.bc.Dsh[d_kb + 2][d_row] = v0.z;
                sm.bc.Dsh[d_kb + 3][d_row] = v0.w;
                sm.bc.Dsh[d_kb + 4][d_row] = v1.x;
                sm.bc.Dsh[d_kb + 5][d_row] = v1.y;
                sm.bc.Dsh[d_kb + 6][d_row] = v1.z;
                sm.bc.Dsh[d_kb + 7][d_row] = v1.w;
                __syncthreads();
                #pragma unroll
                for (int kk = 0; kk < BC_KB; ++kk)
                    dacc += sm.bc.Hs[ty][kc * BC_KB + kk] * sm.bc.Dsh[kk][tx];
                __syncthreads();
            }
            const float dval = tanhf(dacc + D_b[jg * BC_BJ + tx]);

            // softmax over 3 logits per batch
            if (tid < BC_BB) {
                const float l0 = sm.bc.logits[tid][0] + A_b[0];
                const float l1 = sm.bc.logits[tid][1] + A_b[1];
                const float l2 = sm.bc.logits[tid][2] + A_b[2];
                const float m = fmaxf(l0, fmaxf(l1, l2));
                const float e0 = expf(l0 - m), e1 = expf(l1 - m), e2 = expf(l2 - m);
                const float inv = 1.0f / (e0 + e1 + e2);
                sm.bc.ctrl[tid][0] = e0 * inv;   // push
                sm.bc.ctrl[tid][1] = e1 * inv;   // pop
                sm.bc.ctrl[tid][2] = e2 * inv;   // noop
            }
            __syncthreads();

            // stack update: thread owns column (b, j) over all depths (in-place)
            {
                const int b = bg * BC_BB + ty;
                const int jj = jg * BC_BJ + tx;
                const float a_push = sm.bc.ctrl[ty][0];
                const float a_pop  = sm.bc.ctrl[ty][1];
                const float a_noop = sm.bc.ctrl[ty][2];
                float* scol = ws_stack + (size_t)b * SDEP * SWID + jj;
                float prev = dval;            // stack_up[0] = d
                float cur = scol[0];
                for (int k = 0; k < SDEP; ++k) {
                    const float nxt = (k < SDEP - 1) ? scol[(size_t)(k + 1) * SWID] : 0.0f;
                    scol[(size_t)k * SWID] = a_noop * cur + a_push * prev + a_pop * nxt;
                    prev = cur;
                    cur = nxt;
                }
            }
        }
        grid_barrier(bar, bar_target); bar_target += NBLK;
    }

    // ---- final outputs: hn, cn, stackn appended after outs ----
    {
        const size_t outs_sz = (size_t)S_LEN * BATCH * HDIM;
        const float4* hsrc = (const float4*)(out + (size_t)(S_LEN - 1) * BATCH * HDIM);
        float4* hdst = (float4*)(out + outs_sz);
        const int h4 = (BATCH * HDIM) / 4;
        for (int i = gtid; i < h4; i += gstride) hdst[i] = hsrc[i];
        const float4* csrc = (const float4*)ws_c;
        float4* cdst = (float4*)(out + outs_sz + (size_t)BATCH * HDIM);
        for (int i = gtid; i < h4; i += gstride) cdst[i] = csrc[i];
        const float4* ssrc = (const float4*)ws_stack;
        float4* sdst = (float4*)(out + outs_sz + 2 * (size_t)BATCH * HDIM);
        const int s4 = (BATCH * SDEP * SWID) / 4;
        for (int i = gtid; i < s4; i += gstride) sdst[i] = ssrc[i];
    }
}

extern "C" void kernel_launch(void* const* d_in, const int* in_sizes, int n_in,
                              void* d_out, int out_size, void* d_ws, size_t ws_size,
                              hipStream_t stream) {
    (void)in_sizes; (void)n_in; (void)out_size; (void)ws_size;
    const float* x      = (const float*)d_in[0];
    const float* h0     = (const float*)d_in[1];
    const float* c0     = (const float*)d_in[2];
    const float* stack0 = (const float*)d_in[3];
    const float* W_ih   = (const float*)d_in[4];
    const float* W_hh   = (const float*)d_in[5];
    const float* b_ih   = (const float*)d_in[6];
    const float* b_hh   = (const float*)d_in[7];
    const float* A_w    = (const float*)d_in[8];
    const float* A_b    = (const float*)d_in[9];
    const float* D_w    = (const float*)d_in[10];
    const float* D_b    = (const float*)d_in[11];
    float* out = (float*)d_out;
    float* ws_stack = (float*)d_ws;
    float* ws_c = ws_stack + (size_t)BATCH * SDEP * SWID;
    unsigned* bar = (unsigned*)(ws_c + (size_t)BATCH * HDIM);

    init_barrier_kernel<<<dim3(1), dim3(64), 0, stream>>>(bar);
    stackrnn_kernel<<<dim3(NBLK), dim3(NTHR), 0, stream>>>(
        x, h0, c0, stack0, W_ih, W_hh, b_ih, b_hh,
        A_w, A_b, D_w, D_b, out, ws_stack, ws_c, bar);
}